// Round 1
// 579.047 us; speedup vs baseline: 1.0665x; 1.0665x over previous
//
#include <hip/hip_runtime.h>
#include <math.h>

// CRF-RNN mean-field, MI355X.  seg:[4][21][4096] f32, W:[4][4096][4096] f32, wc:[21][21] f32.
// qVals_{t+1}[b,d,m] = seg[b,d,m] - sum_e wc[d,e] * (sum_n Q_t[b,e,n] * D[b,m,n]),
//   D = W / rowsum(W), precomputed ONCE as bf16 (128 MiB, Infinity-Cache resident),
//   Q_t = softmax_d(qVals_t), stored bf16 class-major with 32-class stride.
//
// iter_k (round-4 rewrite): A (D-tile) is now staged through LDS with
// global_load_lds width=16 — each staging instruction reads 1 KiB CONTIGUOUS
// (one 512-k row chunk), fixing the previous 64B-granule 16-row-scatter DRAM
// pattern that left iter_k ~5-10x over its byte floor. K-split moved from
// wave-level to chunk-level: all 4 waves share each staged [16][512] chunk,
// wave w computes the k-quarter [w*128, w*128+128). LDS layout uses the
// pre-swizzled-global-source pattern (linear LDS dest, XOR (row&7)<<4 on the
// per-lane global byte offset) so the ds_read_b128 A-fragment reads are
// exactly 8-way bank-uniform = conflict-free. Double-buffered, one barrier
// per chunk (m97 structure: stage(c+1) issued before compute(c), drained at
// the end-of-chunk barrier). B (Q, 1 MiB) stays direct-from-global: L2-hot.
// C-partials (16x32 f32, one per wave) reduced via LDS (Cf aliases the stage
// buffer — last DMA into buf0 drains 2 chunks before the dump); epilogue
// fuses compat mix, seg-subtract, and next iteration's softmax.
// Pad classes 21..31 are never written: their C columns are computed from
// garbage but provably never consumed (columns independent; only 0..20 read).
// Q ping-pong: buffer A in ws, buffer B aliased onto d_out (dead until last iter).

#define DC 21
#define DCP 32
#define NN 4096
#define BS 4

typedef unsigned int u32;
typedef unsigned short u16;
typedef short s8v __attribute__((ext_vector_type(8)));
typedef float f4v __attribute__((ext_vector_type(4)));

typedef __attribute__((address_space(1))) const unsigned int as1_u32;
typedef __attribute__((address_space(3))) unsigned int as3_u32;

__device__ __forceinline__ u16 f2bf(float f) {
    u32 u = __float_as_uint(f);
    u = u + 0x7fffu + ((u >> 16) & 1u);   // RNE
    return (u16)(u >> 16);
}

// ---- one-time: rowsum + normalize + fp32->bf16 (one wave per W row) ----
__global__ __launch_bounds__(64) void prep_k(const float* __restrict__ W,
                                             u16* __restrict__ D) {
    const int m = blockIdx.x;            // b*4096 + row
    const int l = threadIdx.x;
    const float4* Wr = (const float4*)(W + (size_t)m * NN) + l;
    float4 v[16];
    float s = 0.f;
#pragma unroll
    for (int i = 0; i < 16; ++i) {
        v[i] = Wr[i * 64];
        s += (v[i].x + v[i].y) + (v[i].z + v[i].w);
    }
#pragma unroll
    for (int off = 1; off < 64; off <<= 1) s += __shfl_xor(s, off);
    const float inv = 1.f / s;
    u32* Dr = (u32*)(D + (size_t)m * NN);
#pragma unroll
    for (int i = 0; i < 16; ++i) {
        u32 p0 = (u32)f2bf(v[i].x * inv) | ((u32)f2bf(v[i].y * inv) << 16);
        u32 p1 = (u32)f2bf(v[i].z * inv) | ((u32)f2bf(v[i].w * inv) << 16);
        *(uint2*)(Dr + i * 128 + l * 2) = make_uint2(p0, p1);
    }
}

// ---- initial softmax: seg f32 -> Q bf16 (classes 0..20 only; pads stay garbage) ----
__global__ __launch_bounds__(256) void softmax0_k(const float* __restrict__ x,
                                                  u16* __restrict__ q) {
    unsigned gid = blockIdx.x * 256u + threadIdx.x;
    unsigned b = gid >> 12, n = gid & 4095u;
    const float* xb = x + (size_t)b * DC * NN + n;
    float v[DC];
    float m = -1e30f;
#pragma unroll
    for (int d = 0; d < DC; ++d) { v[d] = xb[(size_t)d * NN]; m = fmaxf(m, v[d]); }
    float s = 0.f;
#pragma unroll
    for (int d = 0; d < DC; ++d) { v[d] = __expf(v[d] - m); s += v[d]; }
    float inv = 1.f / s;
    u16* qb = q + (size_t)b * DCP * NN + n;
#pragma unroll
    for (int d = 0; d < DC; ++d) qb[(size_t)d * NN] = f2bf(v[d] * inv);
}

// ---- main iteration: LDS-staged MFMA GEMM + fused epilogue ----
__global__ __launch_bounds__(256, 4) void iter_k(const u16* __restrict__ Q,
                                                 const u16* __restrict__ D,
                                                 const float* __restrict__ wc,
                                                 const float* __restrict__ seg,
                                                 u16* __restrict__ qnext,
                                                 float* __restrict__ out,
                                                 int last) {
    // A-tile stage: 2 x [16 rows][1 KiB row-chunk] = 32 KiB, linear layout,
    // content swizzled via pre-swizzled global source (bank-conflict-free reads).
    __shared__ __align__(16) char sA[2][16 * 1024];
    __shared__ float wcs[DC * DC];
    float (*Cf)[16][DCP] = (float (*)[16][DCP])&sA[0][0];   // aliased after k-loop

    const int tid = threadIdx.x;
    const int w   = tid >> 6;            // wave id = k-quarter within each chunk
    const int l   = tid & 63;
    const int b   = blockIdx.x >> 8;
    const int m0  = (blockIdx.x & 255) * 16;

    for (int i = tid; i < DC * DC; i += 256) wcs[i] = wc[i];

    const int r  = l & 15;               // A row / B class index
    const int q4 = l >> 4;               // quad: k-run offset q4*8

    const u16* Db = D + ((size_t)b * NN + m0) * NN;               // 16-row tile base
    const u16* Bl = Q + ((size_t)b * DCP + r) * NN + w * 128 + q4 * 8;
    const u16* Bh = Bl + (size_t)16 * NN;

    const int sl16 = l * 16;             // this lane's linear 16B slot in a row-chunk

    f4v clo = {0.f, 0.f, 0.f, 0.f};
    f4v chi = {0.f, 0.f, 0.f, 0.f};

    // Stage chunk c: wave w DMAs rows 4w..4w+3; one instr = one contiguous 1 KiB
    // row-chunk. Global per-lane address carries the XOR swizzle; LDS dest is
    // the linear wave-uniform base (HW adds lane*16).
#define STAGE(c)                                                                    \
    {                                                                               \
        _Pragma("unroll")                                                           \
        for (int rr = 0; rr < 4; ++rr) {                                            \
            const int row = w * 4 + rr;                                             \
            const char* gsrc = (const char*)(Db + (size_t)row * NN + (c) * 512)     \
                               + (sl16 ^ ((row & 7) << 4));                         \
            __builtin_amdgcn_global_load_lds((as1_u32*)gsrc,                        \
                                             (as3_u32*)&sA[(c) & 1][row * 1024],    \
                                             16, 0, 0);                             \
        }                                                                           \
    }

    STAGE(0);
    __syncthreads();

    const int abase = w * 256 + q4 * 16;     // lane's k-run byte offset in row-chunk
    const int aswz  = (r & 7) << 4;          // read-side swizzle (matches source)

#pragma unroll
    for (int c = 0; c < 8; ++c) {
        if (c < 7) STAGE(c + 1);             // DMA next chunk under this chunk's compute
#pragma unroll
        for (int ks = 0; ks < 4; ++ks) {
            s8v a  = *(const s8v*)&sA[c & 1][r * 1024 + ((abase + ks * 64) ^ aswz)];
            s8v bl = *(const s8v*)(Bl + c * 512 + ks * 32);
            s8v bh = *(const s8v*)(Bh + c * 512 + ks * 32);
            clo = __builtin_amdgcn_mfma_f32_16x16x32_bf16(a, bl, clo, 0, 0, 0);
            chi = __builtin_amdgcn_mfma_f32_16x16x32_bf16(a, bh, chi, 0, 0, 0);
        }
        __syncthreads();                     // drains stage(c+1), protects buf swap
    }
#undef STAGE

    // dump partial C: lane holds col=l&15 (class), rows q4*4+i
    // (Cf aliases sA[0]; last DMA into buf0 was chunk 6, drained at barrier c=5)
#pragma unroll
    for (int i = 0; i < 4; ++i) {
        Cf[w][q4 * 4 + i][r]      = clo[i];
        Cf[w][q4 * 4 + i][16 + r] = chi[i];
    }
    __syncthreads();

    // epilogue: thread t -> row = t>>4 (0..15), lg = t&15 (16-lane group per row)
    const int row = tid >> 4;
    const int lg  = tid & 15;
    const int m   = m0 + row;

    float sd[24];
#pragma unroll
    for (int j = 0; j < 6; ++j) {
        float4 v = make_float4(0.f, 0.f, 0.f, 0.f);
#pragma unroll
        for (int w2 = 0; w2 < 4; ++w2) {
            float4 c = *(const float4*)&Cf[w2][row][j * 4];
            v.x += c.x; v.y += c.y; v.z += c.z; v.w += c.w;
        }
        sd[j * 4 + 0] = v.x; sd[j * 4 + 1] = v.y;
        sd[j * 4 + 2] = v.z; sd[j * 4 + 3] = v.w;
    }

    const int d1 = lg;                   // classes 0..15
    const int d2 = 16 + lg;              // classes 16..20 valid iff lg<5
    float u1 = 0.f;
#pragma unroll
    for (int e = 0; e < DC; ++e) u1 += wcs[d1 * DC + e] * sd[e];
    float v1 = seg[((size_t)b * DC + d1) * NN + m] - u1;

    float v2 = -INFINITY;
    if (lg < 5) {
        float u2 = 0.f;
#pragma unroll
        for (int e = 0; e < DC; ++e) u2 += wcs[d2 * DC + e] * sd[e];
        v2 = seg[((size_t)b * DC + d2) * NN + m] - u2;
    }

    if (last) {
        out[((size_t)b * DC + d1) * NN + m] = v1;
        if (lg < 5) out[((size_t)b * DC + d2) * NN + m] = v2;
    } else {
        float mx = fmaxf(v1, v2);
#pragma unroll
        for (int off = 1; off < 16; off <<= 1) mx = fmaxf(mx, __shfl_xor(mx, off));
        float e1 = __expf(v1 - mx);
        float e2 = (lg < 5) ? __expf(v2 - mx) : 0.f;
        float ss = e1 + e2;
#pragma unroll
        for (int off = 1; off < 16; off <<= 1) ss += __shfl_xor(ss, off);
        float inv = 1.f / ss;
        qnext[((size_t)b * DCP + d1) * NN + m] = f2bf(e1 * inv);
        if (lg < 5) qnext[((size_t)b * DCP + d2) * NN + m] = f2bf(e2 * inv);
    }
}

// ======== fp32 fallback (round-2 structure) if ws too small ========
__global__ __launch_bounds__(256) void fb_softmax_k(const float* __restrict__ x,
                                                    float* __restrict__ q) {
    unsigned gid = blockIdx.x * 256u + threadIdx.x;
    unsigned b = gid >> 12, n = gid & 4095u;
    const float* xb = x + (size_t)b * DC * NN + n;
    float v[DC]; float m = -1e30f;
#pragma unroll
    for (int d = 0; d < DC; ++d) { v[d] = xb[(size_t)d * NN]; m = fmaxf(m, v[d]); }
    float s = 0.f;
#pragma unroll
    for (int d = 0; d < DC; ++d) { v[d] = __expf(v[d] - m); s += v[d]; }
    float inv = 1.f / s;
    float* qb = q + (size_t)b * DC * NN + n;
#pragma unroll
    for (int d = 0; d < DC; ++d) qb[(size_t)d * NN] = v[d] * inv;
}

__global__ __launch_bounds__(64) void fb_iter_k(const float* __restrict__ Q,
                                                const float* __restrict__ W,
                                                const float* __restrict__ wc,
                                                const float* __restrict__ seg,
                                                float* __restrict__ qnext,
                                                float* __restrict__ out,
                                                int write_q, int write_out) {
    const int lane = threadIdx.x;
    const int g = lane >> 4, l = lane & 15;
    const int b = blockIdx.x >> 9, rb = blockIdx.x & 511;
    const int m0 = rb * 8 + g * 2;
    const float4* Wr0 = (const float4*)(W + ((size_t)b * NN + m0) * NN + l * 4);
    const float4* Wr1 = (const float4*)(W + ((size_t)b * NN + m0 + 1) * NN + l * 4);
    const float4* Qf4 = (const float4*)(Q + (size_t)b * DC * NN + l * 4);
    float acc0[DC], acc1[DC];
#pragma unroll
    for (int d = 0; d < DC; ++d) { acc0[d] = 0.f; acc1[d] = 0.f; }
    float rs0 = 0.f, rs1 = 0.f;
#pragma unroll 2
    for (int s = 0; s < 64; ++s) {
        float4 wa = Wr0[s * 16], wb = Wr1[s * 16];
        rs0 += (wa.x + wa.y) + (wa.z + wa.w);
        rs1 += (wb.x + wb.y) + (wb.z + wb.w);
#pragma unroll
        for (int d = 0; d < DC; ++d) {
            float4 qv = Qf4[d * 1024 + s * 16];
            acc0[d] += qv.x * wa.x + qv.y * wa.y + qv.z * wa.z + qv.w * wa.w;
            acc1[d] += qv.x * wb.x + qv.y * wb.y + qv.z * wb.z + qv.w * wb.w;
        }
    }
#pragma unroll
    for (int off = 1; off < 16; off <<= 1) {
        rs0 += __shfl_xor(rs0, off); rs1 += __shfl_xor(rs1, off);
#pragma unroll
        for (int d = 0; d < DC; ++d) {
            acc0[d] += __shfl_xor(acc0[d], off);
            acc1[d] += __shfl_xor(acc1[d], off);
        }
    }
    const float inv0 = 1.f / rs0, inv1 = 1.f / rs1;
    const int d1 = l, d2 = l + 16;
    const bool has2 = (d2 < DC);
    float u0a = 0.f, u1a = 0.f, u0b = 0.f, u1b = 0.f;
#pragma unroll
    for (int e = 0; e < DC; ++e) {
        float w1 = wc[d1 * DC + e];
        u0a += w1 * acc0[e]; u1a += w1 * acc1[e];
    }
    if (has2) {
#pragma unroll
        for (int e = 0; e < DC; ++e) {
            float w2 = wc[d2 * DC + e];
            u0b += w2 * acc0[e]; u1b += w2 * acc1[e];
        }
    }
    const size_t base = (size_t)b * DC * NN;
    const size_t i0a = base + (size_t)d1 * NN + m0;
    const size_t i0b = base + (size_t)d2 * NN + m0;
    float v0a = seg[i0a] - u0a * inv0;
    float v1a = seg[i0a + 1] - u1a * inv1;
    float v0b = 0.f, v1b = 0.f;
    if (has2) { v0b = seg[i0b] - u0b * inv0; v1b = seg[i0b + 1] - u1b * inv1; }
    if (write_out) {
        out[i0a] = v0a; out[i0a + 1] = v1a;
        if (has2) { out[i0b] = v0b; out[i0b + 1] = v1b; }
    }
    if (write_q) {
        float mx0 = has2 ? fmaxf(v0a, v0b) : v0a;
        float mx1 = has2 ? fmaxf(v1a, v1b) : v1a;
#pragma unroll
        for (int off = 1; off < 16; off <<= 1) {
            mx0 = fmaxf(mx0, __shfl_xor(mx0, off));
            mx1 = fmaxf(mx1, __shfl_xor(mx1, off));
        }
        float e0a = __expf(v0a - mx0), e1a = __expf(v1a - mx1);
        float e0b = has2 ? __expf(v0b - mx0) : 0.f;
        float e1b = has2 ? __expf(v1b - mx1) : 0.f;
        float s0 = e0a + e0b, s1 = e1a + e1b;
#pragma unroll
        for (int off = 1; off < 16; off <<= 1) {
            s0 += __shfl_xor(s0, off); s1 += __shfl_xor(s1, off);
        }
        float is0 = 1.f / s0, is1 = 1.f / s1;
        qnext[i0a] = e0a * is0; qnext[i0a + 1] = e1a * is1;
        if (has2) { qnext[i0b] = e0b * is0; qnext[i0b + 1] = e1b * is1; }
    }
}

extern "C" void kernel_launch(void* const* d_in, const int* in_sizes, int n_in,
                              void* d_out, int out_size, void* d_ws, size_t ws_size,
                              hipStream_t stream) {
    const float* seg = (const float*)d_in[0];
    const float* W   = (const float*)d_in[1];
    const float* wc  = (const float*)d_in[2];
    float* out = (float*)d_out;

    const size_t needD = (size_t)BS * NN * NN * sizeof(u16);      // 134,217,728
    const size_t needQ = (size_t)BS * DCP * NN * sizeof(u16);     // 1,048,576

    if (ws_size >= needD + needQ && (size_t)out_size * sizeof(float) >= needQ) {
        u16* Dbf = (u16*)d_ws;
        u16* Q0  = (u16*)((char*)d_ws + needD);
        u16* Q1  = (u16*)d_out;          // d_out doubles as Q buffer until last iter

        prep_k<<<dim3(BS * NN), dim3(64), 0, stream>>>(W, Dbf);
        softmax0_k<<<dim3(BS * NN / 256), dim3(256), 0, stream>>>(seg, Q0);

        const u16* qin = Q0;
        u16* qout = Q1;
        for (int it = 0; it < 5; ++it) {
            iter_k<<<dim3(BS * NN / 16), dim3(256), 0, stream>>>(
                qin, Dbf, wc, seg, qout, out, (it == 4) ? 1 : 0);
            const u16* t = qin; qin = qout; qout = (u16*)t;
        }
    } else {
        float* Qa = (float*)d_ws;
        float* Qb = Qa + (size_t)BS * DC * NN;
        fb_softmax_k<<<dim3(BS * NN / 256), dim3(256), 0, stream>>>(seg, Qa);
        const float* qin = Qa;
        float* qout = Qb;
        for (int it = 0; it < 5; ++it) {
            fb_iter_k<<<dim3(2048), dim3(64), 0, stream>>>(
                qin, W, wc, seg, qout, out, (it < 4) ? 1 : 0, (it == 4) ? 1 : 0);
            const float* t = qin; qin = qout; qout = (float*)t;
        }
    }
}

// Round 2
// 457.035 us; speedup vs baseline: 1.3512x; 1.2670x over previous
//
#include <hip/hip_runtime.h>
#include <math.h>

// CRF-RNN mean-field, MI355X.  seg:[4][21][4096] f32, W:[4][4096][4096] f32, wc:[21][21] f32.
// qVals_{t+1}[b,d,m] = seg[b,d,m] - sum_e wc[d,e] * (sum_n Q_t[b,e,n] * D[b,m,n]),
//   D = W / rowsum(W), precomputed ONCE as fp8 e4m3 scaled by 2048 (64 MiB),
//   Q_t = softmax_d(qVals_t), stored fp8 e4m3 class-major with 32-class stride.
//
// Round-5 rewrite:
//  * fp8 e4m3 for D AND Q -> halves the dominant traffic (D re-read 5x).
//    D stored as W*2048/rowsum (values ~[0,1.1], exact pow2 scale folded into wcs).
//    Error analysis: D-quant enters as sum_n D*eps*(sum_e wc*Q) -> sqrt(4096)-
//    suppressed, ~2e-4/iter vs current absmax 0.0156 -> safe.
//  * mfma_f32_16x16x32_fp8_fp8 (long,long,f32x4): same fragment geometry as the
//    proven bf16 16x16x32 path (lane&15 = row/col, (lane>>4)*8 = k-run), 8B frags.
//  * BOTH operands staged via global_load_lds width=16 (kills the 16-segment
//    Q gathers of rounds 0/1).  M-tile = 32 rows, 512 blocks = exactly 2/CU.
//  * T4 counted-vmcnt pipeline: 4 LDS buffers, 3 chunks in flight, per-chunk
//    "s_waitcnt vmcnt(8); s_barrier; sched_barrier(0); issue STAGE(c+3)".
//    Own-wave counted wait BEFORE the barrier => cross-wave completion guarantee
//    (m201 discipline); stage-issue AFTER the barrier => buf[(c+3)&3] cannot land
//    before all waves finished reading chunk c-1 (same buffer).
//  * XOR swizzle ((row&7)<<4) on the per-lane GLOBAL source + on LDS reads
//    (16B granule = DMA lane granule); b64 frag reads are footprint-optimal.
// Epilogue: cross-wave K-split reduce via LDS (Cf aliases buf0 -- last DMA into
// buf0 is chunk 12, all waves past barrier 13 before any Cf write), fused compat
// mix (wc/2048), seg-subtract, and next iteration's softmax -> fp8 Q.
// Pad classes 21..31 never consumed.  Q ping-pong: ws / d_out (dead until last).

#define DC 21
#define DCP 32
#define NN 4096
#define BS 4

typedef unsigned int u32;
typedef unsigned short u16;
typedef unsigned char u8;
typedef float f4v __attribute__((ext_vector_type(4)));

typedef __attribute__((address_space(1))) const unsigned int as1_u32;
typedef __attribute__((address_space(3))) unsigned int as3_u32;

#define WAITVM(n) asm volatile("s_waitcnt vmcnt(" #n ")" ::: "memory")

__device__ __forceinline__ u16 f2bf(float f) {
    u32 u = __float_as_uint(f);
    u = u + 0x7fffu + ((u >> 16) & 1u);   // RNE
    return (u16)(u >> 16);
}

// f32 -> fp8 e4m3fn (RNE), nonneg inputs only (D,Q >= 0), values <= ~4.
__device__ __forceinline__ u8 f2e4(float f) {
    if (!(f >= 0.015625f)) {                       // subnormal region (< 2^-6)
        int q = __float2int_rn(f * 512.0f);        // grid 2^-9; q in 0..8
        return (u8)q;                              // q==8 -> exp1 mant0 = 2^-6 (ok)
    }
    u32 b = __float_as_uint(f);
    b += 0x7FFFFu + ((b >> 20) & 1u);              // RNE into 3-bit mantissa
    return (u8)(((((b >> 23) & 0xFFu) - 120u) << 3) | ((b >> 20) & 7u));
}

// ---- one-time: rowsum + normalize*2048 + fp32->fp8 (one wave per W row) ----
__global__ __launch_bounds__(64) void prep_k(const float* __restrict__ W,
                                             u8* __restrict__ D) {
    const int m = blockIdx.x;            // b*4096 + row
    const int l = threadIdx.x;
    const float4* Wr = (const float4*)(W + (size_t)m * NN) + l;
    float4 v[16];
    float s = 0.f;
#pragma unroll
    for (int i = 0; i < 16; ++i) {
        v[i] = Wr[i * 64];
        s += (v[i].x + v[i].y) + (v[i].z + v[i].w);
    }
#pragma unroll
    for (int off = 1; off < 64; off <<= 1) s += __shfl_xor(s, off);
    const float inv2k = 2048.f / s;      // fold the 2048 pow2 scale here
    u32* Dr = (u32*)(D + (size_t)m * NN);
#pragma unroll
    for (int i = 0; i < 16; ++i) {
        u32 w = (u32)f2e4(v[i].x * inv2k) | ((u32)f2e4(v[i].y * inv2k) << 8) |
                ((u32)f2e4(v[i].z * inv2k) << 16) | ((u32)f2e4(v[i].w * inv2k) << 24);
        Dr[i * 64 + l] = w;
    }
}

// ---- initial softmax: seg f32 -> Q fp8 (classes 0..20 only; pads stay garbage) ----
__global__ __launch_bounds__(256) void softmax0_k(const float* __restrict__ x,
                                                  u8* __restrict__ q) {
    unsigned gid = blockIdx.x * 256u + threadIdx.x;
    unsigned b = gid >> 12, n = gid & 4095u;
    const float* xb = x + (size_t)b * DC * NN + n;
    float v[DC];
    float m = -1e30f;
#pragma unroll
    for (int d = 0; d < DC; ++d) { v[d] = xb[(size_t)d * NN]; m = fmaxf(m, v[d]); }
    float s = 0.f;
#pragma unroll
    for (int d = 0; d < DC; ++d) { v[d] = __expf(v[d] - m); s += v[d]; }
    float inv = 1.f / s;
    u8* qb = q + (size_t)b * DCP * NN + n;
#pragma unroll
    for (int d = 0; d < DC; ++d) qb[(size_t)d * NN] = f2e4(v[d] * inv);
}

// ---- main iteration: fp8 MFMA, dual-operand LDS-DMA, counted-vmcnt pipeline ----
__global__ __launch_bounds__(256, 2) void iter_k(const u8* __restrict__ Q,
                                                 const u8* __restrict__ D,
                                                 const float* __restrict__ wc,
                                                 const float* __restrict__ seg,
                                                 u8* __restrict__ qnext,
                                                 float* __restrict__ out,
                                                 int last) {
    // 4 pipeline buffers; each: A-slab [32 rows][256B] + B-slab [32 cls][256B].
    __shared__ __align__(16) char lds[4][16384];
    __shared__ float wcs[DC * DC];
    float (*Cf)[2][16][DCP] = (float (*)[2][16][DCP])&lds[0][0];   // 16 KiB alias

    const int tid = threadIdx.x;
    const int w   = tid >> 6;            // wave id = k-quarter within each chunk
    const int l   = tid & 63;
    const int b   = blockIdx.x >> 7;
    const int m0  = (blockIdx.x & 127) * 32;

    for (int i = tid; i < DC * DC; i += 256)
        wcs[i] = wc[i] * (1.f / 2048.f);           // undo the D*2048 scale

    const int r  = l & 15;               // A row (within 16-row tile) / B class
    const int q4 = l >> 4;               // k-run offset q4*8 within a K=32 step

    const u8* Db = D + ((size_t)b * NN + m0) * NN;     // 32-row tile base (bytes)
    const u8* Qb = Q + (size_t)b * DCP * NN;           // this batch's Q (bytes)

    // DMA geometry: instr i (0..7) covers rows/cls 4i..4i+3 (1 KiB contiguous LDS).
    // lane j: row = 4i + (j>>4), inner = (j&15)*16, source XOR-swizzled by row.
    const int drow = l >> 4;                 // 0..3 row-within-instr
    const int dinn = (l & 15) * 16;          // 0..240 inner byte offset

    f4v a00 = {0.f,0.f,0.f,0.f}, a01 = {0.f,0.f,0.f,0.f};
    f4v a10 = {0.f,0.f,0.f,0.f}, a11 = {0.f,0.f,0.f,0.f};

#define STAGE(c)                                                                     \
    {                                                                                \
        const int bi_ = (c) & 3;                                                     \
        _Pragma("unroll")                                                            \
        for (int ii = 0; ii < 2; ++ii) {                                             \
            const int i_   = w * 2 + ii;                                             \
            const int row_ = 4 * i_ + drow;                                          \
            const u8* ga = Db + (size_t)row_ * NN + (c) * 256                        \
                           + (dinn ^ ((row_ & 7) << 4));                             \
            __builtin_amdgcn_global_load_lds((as1_u32*)ga,                           \
                (as3_u32*)&lds[bi_][i_ * 1024], 16, 0, 0);                           \
            const u8* gb = Qb + (size_t)row_ * NN + (c) * 256                        \
                           + (dinn ^ ((row_ & 7) << 4));                             \
            __builtin_amdgcn_global_load_lds((as1_u32*)gb,                           \
                (as3_u32*)&lds[bi_][8192 + i_ * 1024], 16, 0, 0);                    \
        }                                                                            \
    }

    STAGE(0);
    STAGE(1);
    STAGE(2);                                 // 12 DMAs/wave in flight

    const int swzr  = (r & 7) << 4;           // read-side swizzle
    const int kbase = w * 64 + q4 * 8;        // this lane's k-run base in a chunk

#pragma unroll
    for (int c = 0; c < 16; ++c) {
        if (c < 14) { WAITVM(8); }            // chunk c's 4 DMAs/wave complete
        else if (c == 14) { WAITVM(4); }
        else { WAITVM(0); }
        __builtin_amdgcn_s_barrier();         // -> complete for ALL waves
        __builtin_amdgcn_sched_barrier(0);
        if (c + 3 < 16) STAGE(c + 3);         // reuses buf[(c-1)&3]: safe after bar

        const char* bufA = &lds[c & 3][0];
        const char* bufB = &lds[c & 3][8192];
#pragma unroll
        for (int ks = 0; ks < 2; ++ks) {
            const int off = kbase + ks * 32;
            long fa0 = *(const long*)&bufA[(r)      * 256 + (off ^ swzr)];
            long fa1 = *(const long*)&bufA[(16 + r) * 256 + (off ^ swzr)];
            long fbl = *(const long*)&bufB[(r)      * 256 + (off ^ swzr)];
            long fbh = *(const long*)&bufB[(16 + r) * 256 + (off ^ swzr)];
            a00 = __builtin_amdgcn_mfma_f32_16x16x32_fp8_fp8(fa0, fbl, a00, 0, 0, 0);
            a01 = __builtin_amdgcn_mfma_f32_16x16x32_fp8_fp8(fa0, fbh, a01, 0, 0, 0);
            a10 = __builtin_amdgcn_mfma_f32_16x16x32_fp8_fp8(fa1, fbl, a10, 0, 0, 0);
            a11 = __builtin_amdgcn_mfma_f32_16x16x32_fp8_fp8(fa1, fbh, a11, 0, 0, 0);
        }
    }
#undef STAGE

    // dump partial C (K-split w): lane holds col=r, rows q4*4+i of each 16-row tile.
    // Cf aliases buf0: last DMA into buf0 = chunk 12; every wave writing here has
    // passed barrier 13 => all waves done reading buf0.  All DMAs drained (vmcnt 0).
#pragma unroll
    for (int i = 0; i < 4; ++i) {
        Cf[w][0][q4 * 4 + i][r]      = a00[i];
        Cf[w][0][q4 * 4 + i][16 + r] = a01[i];
        Cf[w][1][q4 * 4 + i][r]      = a10[i];
        Cf[w][1][q4 * 4 + i][16 + r] = a11[i];
    }
    __syncthreads();

    // epilogue: 2 passes of 16 rows; thread t -> row16 = t>>4, lg = t&15.
    const int row16 = tid >> 4;
    const int lg    = tid & 15;
#pragma unroll
    for (int pass = 0; pass < 2; ++pass) {
        const int m = m0 + pass * 16 + row16;

        float sd[24];
#pragma unroll
        for (int j = 0; j < 6; ++j) {
            float4 v = make_float4(0.f, 0.f, 0.f, 0.f);
#pragma unroll
            for (int w2 = 0; w2 < 4; ++w2) {
                float4 cc = *(const float4*)&Cf[w2][pass][row16][j * 4];
                v.x += cc.x; v.y += cc.y; v.z += cc.z; v.w += cc.w;
            }
            sd[j * 4 + 0] = v.x; sd[j * 4 + 1] = v.y;
            sd[j * 4 + 2] = v.z; sd[j * 4 + 3] = v.w;
        }

        const int d1 = lg;                   // classes 0..15
        const int d2 = 16 + lg;              // classes 16..20 valid iff lg<5
        float u1 = 0.f;
#pragma unroll
        for (int e = 0; e < DC; ++e) u1 += wcs[d1 * DC + e] * sd[e];
        float v1 = seg[((size_t)b * DC + d1) * NN + m] - u1;

        float v2 = -INFINITY;
        if (lg < 5) {
            float u2 = 0.f;
#pragma unroll
            for (int e = 0; e < DC; ++e) u2 += wcs[d2 * DC + e] * sd[e];
            v2 = seg[((size_t)b * DC + d2) * NN + m] - u2;
        }

        if (last) {
            out[((size_t)b * DC + d1) * NN + m] = v1;
            if (lg < 5) out[((size_t)b * DC + d2) * NN + m] = v2;
        } else {
            float mx = fmaxf(v1, v2);
#pragma unroll
            for (int off = 1; off < 16; off <<= 1) mx = fmaxf(mx, __shfl_xor(mx, off));
            float e1 = __expf(v1 - mx);
            float e2 = (lg < 5) ? __expf(v2 - mx) : 0.f;
            float ss = e1 + e2;
#pragma unroll
            for (int off = 1; off < 16; off <<= 1) ss += __shfl_xor(ss, off);
            float inv = 1.f / ss;
            qnext[((size_t)b * DCP + d1) * NN + m] = f2e4(e1 * inv);
            if (lg < 5) qnext[((size_t)b * DCP + d2) * NN + m] = f2e4(e2 * inv);
        }
    }
}

// ======== fp32 fallback (round-2 structure) if ws too small ========
__global__ __launch_bounds__(256) void fb_softmax_k(const float* __restrict__ x,
                                                    float* __restrict__ q) {
    unsigned gid = blockIdx.x * 256u + threadIdx.x;
    unsigned b = gid >> 12, n = gid & 4095u;
    const float* xb = x + (size_t)b * DC * NN + n;
    float v[DC]; float m = -1e30f;
#pragma unroll
    for (int d = 0; d < DC; ++d) { v[d] = xb[(size_t)d * NN]; m = fmaxf(m, v[d]); }
    float s = 0.f;
#pragma unroll
    for (int d = 0; d < DC; ++d) { v[d] = __expf(v[d] - m); s += v[d]; }
    float inv = 1.f / s;
    float* qb = q + (size_t)b * DC * NN + n;
#pragma unroll
    for (int d = 0; d < DC; ++d) qb[(size_t)d * NN] = v[d] * inv;
}

__global__ __launch_bounds__(64) void fb_iter_k(const float* __restrict__ Q,
                                                const float* __restrict__ W,
                                                const float* __restrict__ wc,
                                                const float* __restrict__ seg,
                                                float* __restrict__ qnext,
                                                float* __restrict__ out,
                                                int write_q, int write_out) {
    const int lane = threadIdx.x;
    const int g = lane >> 4, l = lane & 15;
    const int b = blockIdx.x >> 9, rb = blockIdx.x & 511;
    const int m0 = rb * 8 + g * 2;
    const float4* Wr0 = (const float4*)(W + ((size_t)b * NN + m0) * NN + l * 4);
    const float4* Wr1 = (const float4*)(W + ((size_t)b * NN + m0 + 1) * NN + l * 4);
    const float4* Qf4 = (const float4*)(Q + (size_t)b * DC * NN + l * 4);
    float acc0[DC], acc1[DC];
#pragma unroll
    for (int d = 0; d < DC; ++d) { acc0[d] = 0.f; acc1[d] = 0.f; }
    float rs0 = 0.f, rs1 = 0.f;
#pragma unroll 2
    for (int s = 0; s < 64; ++s) {
        float4 wa = Wr0[s * 16], wb = Wr1[s * 16];
        rs0 += (wa.x + wa.y) + (wa.z + wa.w);
        rs1 += (wb.x + wb.y) + (wb.z + wb.w);
#pragma unroll
        for (int d = 0; d < DC; ++d) {
            float4 qv = Qf4[d * 1024 + s * 16];
            acc0[d] += qv.x * wa.x + qv.y * wa.y + qv.z * wa.z + qv.w * wa.w;
            acc1[d] += qv.x * wb.x + qv.y * wb.y + qv.z * wb.z + qv.w * wb.w;
        }
    }
#pragma unroll
    for (int off = 1; off < 16; off <<= 1) {
        rs0 += __shfl_xor(rs0, off); rs1 += __shfl_xor(rs1, off);
#pragma unroll
        for (int d = 0; d < DC; ++d) {
            acc0[d] += __shfl_xor(acc0[d], off);
            acc1[d] += __shfl_xor(acc1[d], off);
        }
    }
    const float inv0 = 1.f / rs0, inv1 = 1.f / rs1;
    const int d1 = l, d2 = l + 16;
    const bool has2 = (d2 < DC);
    float u0a = 0.f, u1a = 0.f, u0b = 0.f, u1b = 0.f;
#pragma unroll
    for (int e = 0; e < DC; ++e) {
        float w1 = wc[d1 * DC + e];
        u0a += w1 * acc0[e]; u1a += w1 * acc1[e];
    }
    if (has2) {
#pragma unroll
        for (int e = 0; e < DC; ++e) {
            float w2 = wc[d2 * DC + e];
            u0b += w2 * acc0[e]; u1b += w2 * acc1[e];
        }
    }
    const size_t base = (size_t)b * DC * NN;
    const size_t i0a = base + (size_t)d1 * NN + m0;
    const size_t i0b = base + (size_t)d2 * NN + m0;
    float v0a = seg[i0a] - u0a * inv0;
    float v1a = seg[i0a + 1] - u1a * inv1;
    float v0b = 0.f, v1b = 0.f;
    if (has2) { v0b = seg[i0b] - u0b * inv0; v1b = seg[i0b + 1] - u1b * inv1; }
    if (write_out) {
        out[i0a] = v0a; out[i0a + 1] = v1a;
        if (has2) { out[i0b] = v0b; out[i0b + 1] = v1b; }
    }
    if (write_q) {
        float mx0 = has2 ? fmaxf(v0a, v0b) : v0a;
        float mx1 = has2 ? fmaxf(v1a, v1b) : v1a;
#pragma unroll
        for (int off = 1; off < 16; off <<= 1) {
            mx0 = fmaxf(mx0, __shfl_xor(mx0, off));
            mx1 = fmaxf(mx1, __shfl_xor(mx1, off));
        }
        float e0a = __expf(v0a - mx0), e1a = __expf(v1a - mx1);
        float e0b = has2 ? __expf(v0b - mx0) : 0.f;
        float e1b = has2 ? __expf(v1b - mx1) : 0.f;
        float s0 = e0a + e0b, s1 = e1a + e1b;
#pragma unroll
        for (int off = 1; off < 16; off <<= 1) {
            s0 += __shfl_xor(s0, off); s1 += __shfl_xor(s1, off);
        }
        float is0 = 1.f / s0, is1 = 1.f / s1;
        qnext[i0a] = e0a * is0; qnext[i0a + 1] = e1a * is1;
        if (has2) { qnext[i0b] = e0b * is0; qnext[i0b + 1] = e1b * is1; }
    }
}

extern "C" void kernel_launch(void* const* d_in, const int* in_sizes, int n_in,
                              void* d_out, int out_size, void* d_ws, size_t ws_size,
                              hipStream_t stream) {
    const float* seg = (const float*)d_in[0];
    const float* W   = (const float*)d_in[1];
    const float* wc  = (const float*)d_in[2];
    float* out = (float*)d_out;

    const size_t needD = (size_t)BS * NN * NN * sizeof(u8);       // 67,108,864
    const size_t needQ = (size_t)BS * DCP * NN * sizeof(u8);      // 524,288

    if (ws_size >= needD + needQ && (size_t)out_size * sizeof(float) >= needQ) {
        u8* Dq = (u8*)d_ws;
        u8* Q0 = (u8*)((char*)d_ws + needD);
        u8* Q1 = (u8*)d_out;             // d_out doubles as Q buffer until last iter

        prep_k<<<dim3(BS * NN), dim3(64), 0, stream>>>(W, Dq);
        softmax0_k<<<dim3(BS * NN / 256), dim3(256), 0, stream>>>(seg, Q0);

        const u8* qin = Q0;
        u8* qout = Q1;
        for (int it = 0; it < 5; ++it) {
            iter_k<<<dim3(BS * NN / 32), dim3(256), 0, stream>>>(
                qin, Dq, wc, seg, qout, out, (it == 4) ? 1 : 0);
            const u8* t = qin; qin = qout; qout = (u8*)t;
        }
    } else {
        float* Qa = (float*)d_ws;
        float* Qb = Qa + (size_t)BS * DC * NN;
        fb_softmax_k<<<dim3(BS * NN / 256), dim3(256), 0, stream>>>(seg, Qa);
        const float* qin = Qa;
        float* qout = Qb;
        for (int it = 0; it < 5; ++it) {
            fb_iter_k<<<dim3(2048), dim3(64), 0, stream>>>(
                qin, W, wc, seg, qout, out, (it < 4) ? 1 : 0, (it == 4) ? 1 : 0);
            const float* t = qin; qin = qout; qout = (float*)t;
        }
    }
}